// Round 13
// baseline (135.112 us; speedup 1.0000x reference)
//
#include <hip/hip_runtime.h>
#include <hip/hip_bf16.h>
#include <math.h>

// MIL_Cluster_FC round 13: bf16-A gemm1 (cvt OUT of the inner loop).
//  - R8/R10/R12 invariant: fp32-A gemm1 = 74-76us regardless of occupancy
//    (11% MfmaUtil); the f2bf cvt chain + 2x ds_read on the barrier->MFMA
//    critical path is structural. R9's bf16-A variant measured ~30us.
//  - R13 = R12 skeleton + k_convertlin (pure BW, ~20us) + gemm1b5: 512-thr
//    8-wave 64x128 tile, A gathered bf16 via per-lane global_load_lds source
//    (R9-proven), staging pattern byte-identical to R12's proven gemm2w.
//  - fp32-direct gemm1w kept as small-ws fallback.

#define C_NUM 10
#define D_IN 1024
#define D_H 512
#define D_ATT 256
#define N_CLS 4
#define BM 128      // bucket region alignment
#define BMG 64      // gemm row tile
#define BN 128
#define BKS 64

typedef __attribute__((ext_vector_type(8))) short short8v;
typedef __attribute__((ext_vector_type(4))) short short4v;
typedef __attribute__((ext_vector_type(4))) float f32x4;

__device__ __forceinline__ short f2bf(float f) {
    __hip_bfloat16 h = __float2bfloat16(f);
    return *reinterpret_cast<short*>(&h);
}

__device__ __forceinline__ void gload_lds16(const void* g, void* l) {
    __builtin_amdgcn_global_load_lds((const __attribute__((address_space(1))) unsigned int*)g,
                                     (__attribute__((address_space(3))) unsigned int*)l,
                                     16, 0, 0);
}

// bijective XCD-chunked swizzle (m204)
__device__ __forceinline__ int xcd_swizzle(int orig, int nwg) {
    int q = nwg >> 3, r = nwg & 7;
    int xcd = orig & 7, base = orig >> 3;
    return (xcd < r ? xcd * (q + 1) : r * (q + 1) + (xcd - r) * q) + base;
}

// LDS-aggregated histogram
__global__ __launch_bounds__(256) void k_hist(const int* __restrict__ cid, int* counts, int n) {
    __shared__ int lc[C_NUM];
    int tid = threadIdx.x;
    if (tid < C_NUM) lc[tid] = 0;
    __syncthreads();
    int i = blockIdx.x * 256 + tid;
    if (i < n) atomicAdd(&lc[cid[i]], 1);
    __syncthreads();
    if (tid < C_NUM && lc[tid] > 0) atomicAdd(&counts[tid], lc[tid]);
}

// LDS-aggregated scatter + local prefix offsets + pad fill (block 0)
__global__ __launch_bounds__(256) void k_scatter(const int* __restrict__ cid, int* cursor,
                                                 const int* __restrict__ counts,
                                                 int* bucket, int n) {
    __shared__ int lc[C_NUM];
    __shared__ int basev[C_NUM];
    __shared__ int loff[C_NUM + 1];
    int tid = threadIdx.x;
    if (tid < C_NUM) lc[tid] = 0;
    if (tid == 0) {
        int off = 0;
        for (int c2 = 0; c2 < C_NUM; ++c2) {
            loff[c2] = off;
            off += ((counts[c2] + BM - 1) / BM) * BM;
        }
        loff[C_NUM] = off;
    }
    __syncthreads();
    int i = blockIdx.x * 256 + tid;
    int c = 0, lpos = 0;
    bool valid = (i < n);
    if (valid) { c = cid[i]; lpos = atomicAdd(&lc[c], 1); }
    __syncthreads();
    if (tid < C_NUM) basev[tid] = (lc[tid] > 0) ? atomicAdd(&cursor[tid], lc[tid]) : 0;
    __syncthreads();
    if (valid) bucket[loff[c] + basev[c] + lpos] = i;
    if (blockIdx.x == 0) {
        for (int c2 = 0; c2 < C_NUM; ++c2)
            for (int p = loff[c2] + counts[c2] + tid; p < loff[c2 + 1]; p += 256)
                bucket[p] = -1;
    }
}

// linear fp32 -> bf16 cast of x (coalesced, no gather, no bucket dep)
__global__ __launch_bounds__(256) void k_convertlin(const float* __restrict__ x,
                                                    short* __restrict__ xbl) {
    size_t i = (size_t)blockIdx.x * 256 + threadIdx.x;
    const f32x4* p = (const f32x4*)(x + i * 8);
    f32x4 f0 = p[0], f1 = p[1];
    short8v v;
#pragma unroll
    for (int e = 0; e < 4; ++e) { v[e] = f2bf(f0[e]); v[4 + e] = f2bf(f1[e]); }
    *(short8v*)&xbl[i * 8] = v;
}

// merged W1+W2 transpose: [C][K][N] fp32 -> [C][N][K] bf16
__global__ __launch_bounds__(256) void k_transpose2(
    const float* __restrict__ W1, short* __restrict__ Wt1,
    const float* __restrict__ W2, short* __restrict__ Wt2)
{
    __shared__ float t[64][65];
    int bid = blockIdx.x;
    const float* src; short* dst; int K, N, k0, n0;
    if (bid < C_NUM * 128) {
        int cc = bid >> 7, r = bid & 127;
        k0 = (r & 15) * 64; n0 = (r >> 4) * 64;
        src = W1 + (size_t)cc * D_IN * D_H; dst = Wt1 + (size_t)cc * D_H * D_IN;
        K = D_IN; N = D_H;
    } else {
        int idx = bid - C_NUM * 128;
        int cc = idx >> 6, r = idx & 63;
        k0 = (r & 7) * 64; n0 = (r >> 3) * 64;
        src = W2 + (size_t)cc * D_H * D_H; dst = Wt2 + (size_t)cc * D_H * D_H;
        K = D_H; N = D_H;
    }
    int tid = threadIdx.x;
    int tk = tid >> 4, tn4 = (tid & 15) * 4;
#pragma unroll
    for (int it = 0; it < 4; ++it) {
        int k = tk + it * 16;
        f32x4 v = *(const f32x4*)&src[(size_t)(k0 + k) * N + n0 + tn4];
        t[k][tn4 + 0] = v[0]; t[k][tn4 + 1] = v[1];
        t[k][tn4 + 2] = v[2]; t[k][tn4 + 3] = v[3];
    }
    __syncthreads();
    int wn = tid >> 2, kq = (tid & 3) * 16;
#pragma unroll
    for (int q = 0; q < 4; ++q) {
        int k = kq + q * 4;
        short4v o;
#pragma unroll
        for (int e = 0; e < 4; ++e) o[e] = f2bf(t[k + e][wn]);
        *(short4v*)&dst[(size_t)(n0 + wn) * K + k0 + k] = o;
    }
}

// gemm1 (bf16 A, 512 threads, 8 waves 2x4, 64x128 tile):
// h1 = relu(xbl[bucket] @ W1t^T + b1)
__global__ __launch_bounds__(512) void k_gemm1b5(
    const short* __restrict__ xbl, const short* __restrict__ Wt, const float* __restrict__ b1,
    const int* __restrict__ bucket, const int* __restrict__ counts, short* __restrict__ h1)
{
    __shared__ short As[BMG * BKS];    // 8 KB
    __shared__ short Bs[BN * BKS];     // 16 KB
    __shared__ int ridx[BMG];
    __shared__ int saoff[C_NUM + 1];

    int tid = threadIdx.x;
    int wg = xcd_swizzle(blockIdx.x, gridDim.x);
    int rowStart = (wg >> 2) * BMG;
    int colStart = (wg & 3) * BN;

    if (tid == 0) {
        int off = 0;
        for (int c2 = 0; c2 < C_NUM; ++c2) {
            saoff[c2] = off;
            off += ((counts[c2] + BM - 1) / BM) * BM;
        }
        saoff[C_NUM] = off;
    }
    if (tid < BMG) ridx[tid] = bucket[rowStart + tid];
    __syncthreads();
    if (rowStart >= saoff[C_NUM]) return;
    int c = 0;
    while (c < C_NUM - 1 && rowStart >= saoff[c + 1]) ++c;

    int lane = tid & 63;
    int wid = tid >> 6;          // 0..7
    int wm = wid >> 2;           // 0..1
    int wn = wid & 3;            // 0..3

    int l8 = lane >> 3;
    int sslot = (lane & 7) ^ l8;
    // A gather: wave wid covers rows wid*8 + l8 (gathered via bucket)
    int arow = wid * 8 + l8;
    int rr = ridx[arow];
    const short* abase = xbl + (size_t)(rr < 0 ? 0 : rr) * D_IN + sslot * 8;
    // B: rows q*64 + wid*8 + l8
    const short* bq[2];
#pragma unroll
    for (int q = 0; q < 2; ++q) {
        int rowb = q * 64 + wid * 8 + l8;
        bq[q] = Wt + ((size_t)c * D_H + colStart + rowb) * D_IN + sslot * 8;
    }

    f32x4 acc[2][2];
#pragma unroll
    for (int i = 0; i < 2; ++i)
#pragma unroll
        for (int j = 0; j < 2; ++j)
            acc[i][j] = f32x4{0.f, 0.f, 0.f, 0.f};

    for (int k0 = 0; k0 < D_IN; k0 += BKS) {
        gload_lds16(abase + k0, &As[(wid * 8) * BKS]);
        gload_lds16(bq[0] + k0, &Bs[(wid * 8) * BKS]);
        gload_lds16(bq[1] + k0, &Bs[(64 + wid * 8) * BKS]);
        __syncthreads();
#pragma unroll
        for (int kk = 0; kk < 2; ++kk) {
            short8v af[2], bfr[2];
#pragma unroll
            for (int i = 0; i < 2; ++i) {
                int row = wm * 32 + i * 16 + (lane & 15);
                int slot = (kk * 4 + (lane >> 4)) ^ (row & 7);
                af[i] = *(const short8v*)&As[row * BKS + slot * 8];
            }
#pragma unroll
            for (int j = 0; j < 2; ++j) {
                int nn = wn * 32 + j * 16 + (lane & 15);
                int slot = (kk * 4 + (lane >> 4)) ^ (nn & 7);
                bfr[j] = *(const short8v*)&Bs[nn * BKS + slot * 8];
            }
#pragma unroll
            for (int i = 0; i < 2; ++i)
#pragma unroll
                for (int j = 0; j < 2; ++j)
                    acc[i][j] = __builtin_amdgcn_mfma_f32_16x16x32_bf16(af[i], bfr[j], acc[i][j], 0, 0, 0);
        }
        __syncthreads();
    }

    const float* bias = b1 + c * D_H;
    float bj[2];
#pragma unroll
    for (int j = 0; j < 2; ++j) bj[j] = bias[colStart + wn * 32 + j * 16 + (lane & 15)];
#pragma unroll
    for (int i = 0; i < 2; ++i) {
#pragma unroll
        for (int r = 0; r < 4; ++r) {
            int rowl = wm * 32 + i * 16 + (lane >> 4) * 4 + r;
            bool valid = (ridx[rowl] >= 0);
            size_t gro = (size_t)(rowStart + rowl) * D_H + colStart + wn * 32 + (lane & 15);
#pragma unroll
            for (int j = 0; j < 2; ++j) {
                float v = valid ? fmaxf(acc[i][j][r] + bj[j], 0.f) : 0.f;
                h1[gro + j * 16] = f2bf(v);
            }
        }
    }
}

// gemm1 fallback (small ws): fp32-direct A, 512 threads (R12-proven)
__global__ __launch_bounds__(512) void k_gemm1w(
    const float* __restrict__ x, const short* __restrict__ Wt, const float* __restrict__ b1,
    const int* __restrict__ bucket, const int* __restrict__ counts, short* __restrict__ h1)
{
    __shared__ float Asf[BMG * BKS];
    __shared__ short Bs[BN * BKS];
    __shared__ int ridx[BMG];
    __shared__ int saoff[C_NUM + 1];

    int tid = threadIdx.x;
    int wg = xcd_swizzle(blockIdx.x, gridDim.x);
    int rowStart = (wg >> 2) * BMG;
    int colStart = (wg & 3) * BN;

    if (tid == 0) {
        int off = 0;
        for (int c2 = 0; c2 < C_NUM; ++c2) {
            saoff[c2] = off;
            off += ((counts[c2] + BM - 1) / BM) * BM;
        }
        saoff[C_NUM] = off;
    }
    if (tid < BMG) ridx[tid] = bucket[rowStart + tid];
    __syncthreads();
    if (rowStart >= saoff[C_NUM]) return;
    int c = 0;
    while (c < C_NUM - 1 && rowStart >= saoff[c + 1]) ++c;

    int lane = tid & 63;
    int wid = tid >> 6;
    int wm = wid >> 2, wn = wid & 3;

    const float* aq[2];
#pragma unroll
    for (int q = 0; q < 2; ++q) {
        int row = q * 32 + wid * 4 + (lane >> 4);
        int rr = ridx[row];
        int srcslot = (lane & 15) ^ (row & 15);
        aq[q] = x + (size_t)(rr < 0 ? 0 : rr) * D_IN + srcslot * 4;
    }
    int l8 = lane >> 3;
    int sslot = (lane & 7) ^ l8;
    const short* bq[2];
#pragma unroll
    for (int q = 0; q < 2; ++q) {
        int rowb = q * 64 + wid * 8 + l8;
        bq[q] = Wt + ((size_t)c * D_H + colStart + rowb) * D_IN + sslot * 8;
    }

    f32x4 acc[2][2];
#pragma unroll
    for (int i = 0; i < 2; ++i)
#pragma unroll
        for (int j = 0; j < 2; ++j)
            acc[i][j] = f32x4{0.f, 0.f, 0.f, 0.f};

    for (int k0 = 0; k0 < D_IN; k0 += BKS) {
        gload_lds16(bq[0] + k0, &Bs[(wid * 8) * BKS]);
        gload_lds16(bq[1] + k0, &Bs[(64 + wid * 8) * BKS]);
        gload_lds16(aq[0] + k0, &Asf[(wid * 4) * BKS]);
        gload_lds16(aq[1] + k0, &Asf[(32 + wid * 4) * BKS]);
        __syncthreads();
#pragma unroll
        for (int kk = 0; kk < 2; ++kk) {
            short8v af[2], bfr[2];
#pragma unroll
            for (int i = 0; i < 2; ++i) {
                int row = wm * 32 + i * 16 + (lane & 15);
                int s8 = kk * 4 + (lane >> 4);
                int p0 = (2 * s8) ^ (row & 15);
                int p1 = (2 * s8 + 1) ^ (row & 15);
                f32x4 lo = *(const f32x4*)&Asf[row * BKS + p0 * 4];
                f32x4 hi = *(const f32x4*)&Asf[row * BKS + p1 * 4];
                short8v v;
#pragma unroll
                for (int e = 0; e < 4; ++e) { v[e] = f2bf(lo[e]); v[4 + e] = f2bf(hi[e]); }
                af[i] = v;
            }
#pragma unroll
            for (int j = 0; j < 2; ++j) {
                int nn = wn * 32 + j * 16 + (lane & 15);
                int slot = (kk * 4 + (lane >> 4)) ^ (nn & 7);
                bfr[j] = *(const short8v*)&Bs[nn * BKS + slot * 8];
            }
#pragma unroll
            for (int i = 0; i < 2; ++i)
#pragma unroll
                for (int j = 0; j < 2; ++j)
                    acc[i][j] = __builtin_amdgcn_mfma_f32_16x16x32_bf16(af[i], bfr[j], acc[i][j], 0, 0, 0);
        }
        __syncthreads();
    }

    const float* bias = b1 + c * D_H;
    float bj[2];
#pragma unroll
    for (int j = 0; j < 2; ++j) bj[j] = bias[colStart + wn * 32 + j * 16 + (lane & 15)];
#pragma unroll
    for (int i = 0; i < 2; ++i) {
#pragma unroll
        for (int r = 0; r < 4; ++r) {
            int rowl = wm * 32 + i * 16 + (lane >> 4) * 4 + r;
            bool valid = (ridx[rowl] >= 0);
            size_t gro = (size_t)(rowStart + rowl) * D_H + colStart + wn * 32 + (lane & 15);
#pragma unroll
            for (int j = 0; j < 2; ++j) {
                float v = valid ? fmaxf(acc[i][j][r] + bj[j], 0.f) : 0.f;
                h1[gro + j * 16] = f2bf(v);
            }
        }
    }
}

// gemm2: 512 threads, 8 waves, 64x128 tile (R12-proven)
__global__ __launch_bounds__(512) void k_gemm2w(
    const short* __restrict__ h1, const short* __restrict__ Wt, const float* __restrict__ b2,
    const int* __restrict__ bucket, const int* __restrict__ counts, float* __restrict__ pooled)
{
    __shared__ short As[BMG * BKS];
    __shared__ short Bs[BN * BKS];
    __shared__ int ridx[BMG];
    __shared__ int saoff[C_NUM + 1];

    int tid = threadIdx.x;
    int wg = xcd_swizzle(blockIdx.x, gridDim.x);
    int rowStart = (wg >> 2) * BMG;
    int colStart = (wg & 3) * BN;

    if (tid == 0) {
        int off = 0;
        for (int c2 = 0; c2 < C_NUM; ++c2) {
            saoff[c2] = off;
            off += ((counts[c2] + BM - 1) / BM) * BM;
        }
        saoff[C_NUM] = off;
    }
    if (tid < BMG) ridx[tid] = bucket[rowStart + tid];
    __syncthreads();
    if (rowStart >= saoff[C_NUM]) return;
    int c = 0;
    while (c < C_NUM - 1 && rowStart >= saoff[c + 1]) ++c;

    int lane = tid & 63;
    int wid = tid >> 6;
    int wm = wid >> 2, wn = wid & 3;

    int l8 = lane >> 3;
    int sslot = (lane & 7) ^ l8;
    const short* abase = h1 + (size_t)(rowStart + wid * 8 + l8) * D_H + sslot * 8;
    const short* bq[2];
#pragma unroll
    for (int q = 0; q < 2; ++q) {
        int rowb = q * 64 + wid * 8 + l8;
        bq[q] = Wt + ((size_t)c * D_H + colStart + rowb) * D_H + sslot * 8;
    }

    f32x4 acc[2][2];
#pragma unroll
    for (int i = 0; i < 2; ++i)
#pragma unroll
        for (int j = 0; j < 2; ++j)
            acc[i][j] = f32x4{0.f, 0.f, 0.f, 0.f};

    for (int k0 = 0; k0 < D_H; k0 += BKS) {
        gload_lds16(abase + k0, &As[(wid * 8) * BKS]);
        gload_lds16(bq[0] + k0, &Bs[(wid * 8) * BKS]);
        gload_lds16(bq[1] + k0, &Bs[(64 + wid * 8) * BKS]);
        __syncthreads();
#pragma unroll
        for (int kk = 0; kk < 2; ++kk) {
            short8v af[2], bfr[2];
#pragma unroll
            for (int i = 0; i < 2; ++i) {
                int row = wm * 32 + i * 16 + (lane & 15);
                int slot = (kk * 4 + (lane >> 4)) ^ (row & 7);
                af[i] = *(const short8v*)&As[row * BKS + slot * 8];
            }
#pragma unroll
            for (int j = 0; j < 2; ++j) {
                int nn = wn * 32 + j * 16 + (lane & 15);
                int slot = (kk * 4 + (lane >> 4)) ^ (nn & 7);
                bfr[j] = *(const short8v*)&Bs[nn * BKS + slot * 8];
            }
#pragma unroll
            for (int i = 0; i < 2; ++i)
#pragma unroll
                for (int j = 0; j < 2; ++j)
                    acc[i][j] = __builtin_amdgcn_mfma_f32_16x16x32_bf16(af[i], bfr[j], acc[i][j], 0, 0, 0);
        }
        __syncthreads();
    }

    const float* bias = b2 + c * D_H;
    float bj[2];
#pragma unroll
    for (int j = 0; j < 2; ++j) bj[j] = bias[colStart + wn * 32 + j * 16 + (lane & 15)];
    float csum[2] = {0.f, 0.f};
#pragma unroll
    for (int i = 0; i < 2; ++i) {
#pragma unroll
        for (int r = 0; r < 4; ++r) {
            int rowl = wm * 32 + i * 16 + (lane >> 4) * 4 + r;
            float m = (ridx[rowl] >= 0) ? 1.f : 0.f;
#pragma unroll
            for (int j = 0; j < 2; ++j)
                csum[j] += m * fmaxf(acc[i][j][r] + bj[j], 0.f);
        }
    }
#pragma unroll
    for (int j = 0; j < 2; ++j) {
        float s = csum[j];
        s += __shfl_xor(s, 16, 64);
        s += __shfl_xor(s, 32, 64);
        if ((lane >> 4) == 0)
            atomicAdd(&pooled[c * D_H + colStart + wn * 32 + j * 16 + lane], s);
    }
}

// ---- tail stage A ----
__global__ __launch_bounds__(256) void k_tA(
    const float* __restrict__ pooled, const int* __restrict__ counts,
    const float* __restrict__ Wfc, const float* __restrict__ bfc,
    float* __restrict__ hfc)
{
    __shared__ float hcs[C_NUM][D_H];
    __shared__ float red[4][64][C_NUM];
    int tid = threadIdx.x;
    for (int idx = tid; idx < C_NUM * D_H; idx += 256) {
        int cc = idx >> 9;
        hcs[cc][idx & (D_H - 1)] = pooled[idx] / fmaxf((float)counts[cc], 1.f);
    }
    __syncthreads();
    int col = blockIdx.x * 64 + (tid & 63);
    int kq = tid >> 6, k0 = kq * 128;
    float acc[C_NUM] = {};
    for (int k = 0; k < 128; ++k) {
        float wv = Wfc[(size_t)(k0 + k) * D_H + col];
#pragma unroll
        for (int cc = 0; cc < C_NUM; ++cc) acc[cc] += hcs[cc][k0 + k] * wv;
    }
#pragma unroll
    for (int cc = 0; cc < C_NUM; ++cc) red[kq][tid & 63][cc] = acc[cc];
    __syncthreads();
    if (kq == 0) {
        float bv = bfc[col];
#pragma unroll
        for (int cc = 0; cc < C_NUM; ++cc) {
            float s = red[0][tid][cc] + red[1][tid][cc] + red[2][tid][cc] + red[3][tid][cc];
            hfc[cc * D_H + col] = fmaxf(s + bv, 0.f);
        }
    }
}

// ---- tail stage B ----
__global__ __launch_bounds__(256) void k_tB(
    const float* __restrict__ hfc,
    const float* __restrict__ Wa, const float* __restrict__ ba,
    const float* __restrict__ Wb, const float* __restrict__ bb,
    const float* __restrict__ Wc,
    float* __restrict__ scores)
{
    __shared__ float hfs[C_NUM][D_H];
    __shared__ float red[4][64][C_NUM][2];
    int tid = threadIdx.x;
    for (int idx = tid; idx < C_NUM * D_H; idx += 256) {
        hfs[idx >> 9][idx & (D_H - 1)] = hfc[idx];
    }
    __syncthreads();
    int ad = blockIdx.x * 64 + (tid & 63);
    int kq = tid >> 6, k0 = kq * 128;
    float sa[C_NUM] = {}, sb[C_NUM] = {};
    for (int k = 0; k < 128; ++k) {
        float wav = Wa[(size_t)(k0 + k) * D_ATT + ad];
        float wbv = Wb[(size_t)(k0 + k) * D_ATT + ad];
#pragma unroll
        for (int cc = 0; cc < C_NUM; ++cc) {
            float h = hfs[cc][k0 + k];
            sa[cc] += h * wav;
            sb[cc] += h * wbv;
        }
    }
#pragma unroll
    for (int cc = 0; cc < C_NUM; ++cc) {
        red[kq][tid & 63][cc][0] = sa[cc];
        red[kq][tid & 63][cc][1] = sb[cc];
    }
    __syncthreads();
    if (kq == 0) {
        float bav = ba[ad], bbv = bb[ad], wcv = Wc[ad];
#pragma unroll
        for (int cc = 0; cc < C_NUM; ++cc) {
            float sat = red[0][tid][cc][0] + red[1][tid][cc][0] + red[2][tid][cc][0] + red[3][tid][cc][0];
            float sbt = red[0][tid][cc][1] + red[1][tid][cc][1] + red[2][tid][cc][1] + red[3][tid][cc][1];
            float v = tanhf(sat + bav) * (1.f / (1.f + expf(-(sbt + bbv)))) * wcv;
            v += __shfl_xor(v, 1, 64); v += __shfl_xor(v, 2, 64); v += __shfl_xor(v, 4, 64);
            v += __shfl_xor(v, 8, 64); v += __shfl_xor(v, 16, 64); v += __shfl_xor(v, 32, 64);
            if (tid == 0) atomicAdd(&scores[cc], v);
        }
    }
}

// ---- tail C+D+E fused (last-block-done) ----
__global__ __launch_bounds__(256) void k_tCDE(
    const float* __restrict__ scores, const float* __restrict__ bc,
    const float* __restrict__ hfc, const float* __restrict__ Wrho,
    float* __restrict__ hr_raw, int* __restrict__ done,
    const float* __restrict__ brho,
    const float* __restrict__ Wcls, const float* __restrict__ bcls,
    float* __restrict__ out)
{
    __shared__ float hps[32];
    __shared__ int amLast;
    int tid = threadIdx.x;
    int k0 = blockIdx.x * 32;
    if (tid < 32) {
        float sc2[C_NUM];
        float mx = -1e30f;
#pragma unroll
        for (int cc = 0; cc < C_NUM; ++cc) { sc2[cc] = scores[cc] + bc[0]; mx = fmaxf(mx, sc2[cc]); }
        float sum = 0.f;
#pragma unroll
        for (int cc = 0; cc < C_NUM; ++cc) { sc2[cc] = expf(sc2[cc] - mx); sum += sc2[cc]; }
        float s = 0.f;
#pragma unroll
        for (int cc = 0; cc < C_NUM; ++cc) s += (sc2[cc] / sum) * hfc[cc * D_H + k0 + tid];
        hps[tid] = s;
    }
    __syncthreads();
    float acc = 0.f;
#pragma unroll 8
    for (int k = 0; k < 32; ++k)
        acc += hps[k] * Wrho[(size_t)(k0 + k) * D_ATT + tid];
    atomicAdd(&hr_raw[tid], acc);

    __threadfence();
    if (tid == 0) amLast = (atomicAdd(done, 1) == (int)gridDim.x - 1);
    __syncthreads();
    if (!amLast) return;

    __shared__ float cpart[4][N_CLS];
    int lane = tid & 63, w = tid >> 6;
    float hraw = atomicAdd(&hr_raw[tid], 0.f);
    float h = fmaxf(hraw + brho[tid], 0.f);
    f32x4 wv = *(const f32x4*)&Wcls[tid * N_CLS];
    float v[N_CLS];
#pragma unroll
    for (int l = 0; l < N_CLS; ++l) {
        v[l] = h * wv[l];
        v[l] += __shfl_xor(v[l], 1, 64); v[l] += __shfl_xor(v[l], 2, 64);
        v[l] += __shfl_xor(v[l], 4, 64); v[l] += __shfl_xor(v[l], 8, 64);
        v[l] += __shfl_xor(v[l], 16, 64); v[l] += __shfl_xor(v[l], 32, 64);
    }
    if (lane == 0) {
#pragma unroll
        for (int l = 0; l < N_CLS; ++l) cpart[w][l] = v[l];
    }
    __syncthreads();
    if (tid == 0) {
        float lg[N_CLS];
#pragma unroll
        for (int l = 0; l < N_CLS; ++l)
            lg[l] = cpart[0][l] + cpart[1][l] + cpart[2][l] + cpart[3][l] + bcls[l];
        int best = 0;
#pragma unroll
        for (int l = 1; l < N_CLS; ++l) if (lg[l] > lg[best]) best = l;
        float Sv = 1.f;
#pragma unroll
        for (int l = 0; l < N_CLS; ++l) {
            float hz = 1.f / (1.f + expf(-lg[l]));
            out[l] = hz;
            Sv *= (1.f - hz);
            out[4 + l] = Sv;
        }
        out[8] = (float)best;
    }
}

extern "C" void kernel_launch(void* const* d_in, const int* in_sizes, int n_in,
                              void* d_out, int out_size, void* d_ws, size_t ws_size,
                              hipStream_t stream)
{
    const float* x    = (const float*)d_in[0];
    const int*   cid  = (const int*)d_in[1];
    const float* W1   = (const float*)d_in[2];
    const float* b1   = (const float*)d_in[3];
    const float* W2   = (const float*)d_in[4];
    const float* b2   = (const float*)d_in[5];
    const float* Wfc  = (const float*)d_in[6];
    const float* bfc  = (const float*)d_in[7];
    const float* Wa   = (const float*)d_in[8];
    const float* ba   = (const float*)d_in[9];
    const float* Wb   = (const float*)d_in[10];
    const float* bb   = (const float*)d_in[11];
    const float* Wc   = (const float*)d_in[12];
    const float* bc   = (const float*)d_in[13];
    const float* Wrho = (const float*)d_in[14];
    const float* brho = (const float*)d_in[15];
    const float* Wcls = (const float*)d_in[16];
    const float* bcls = (const float*)d_in[17];
    float* out = (float*)d_out;

    int n = in_sizes[0] / D_IN;                       // 20000
    int rowTiles = (n + BM - 1) / BM + C_NUM;         // 128-aligned worst case
    int npadMax = rowTiles * BM;
    int rowTiles64 = rowTiles * 2;

    // workspace layout; leading region zeroed by one memset
    char* w = (char*)d_ws;
    int* counts   = (int*)w;                          // [16]
    int* cursor   = counts + 16;                      // [16]
    float* scores = (float*)(counts + 32);            // [16]
    int* done     = (int*)(scores + 16);              // [16]
    float* hr_raw = (float*)(done + 16);              // [256]
    float* pooled = hr_raw + 256;                     // [5120]
    size_t zero_bytes = (size_t)(16 + 16 + 16 + 16 + 256 + 5120) * 4;
    float* hfc  = pooled + 5120;                      // [5120]
    int* bucket = (int*)(hfc + 5120);                 // [npadMax]
    short* Wt1 = (short*)(bucket + npadMax);          // C*512*1024
    short* Wt2 = Wt1 + (size_t)C_NUM * D_H * D_IN;    // C*512*512
    short* h1  = Wt2 + (size_t)C_NUM * D_H * D_H;     // npadMax*512
    short* xbl = h1 + (size_t)npadMax * D_H;          // n*1024 (big path)
    size_t need_big = (size_t)((char*)(xbl + (size_t)n * D_IN) - w);
    bool big = ws_size >= need_big;

    hipMemsetAsync(w, 0, zero_bytes, stream);

    int nb = (n + 255) / 256;
    k_hist<<<nb, 256, 0, stream>>>(cid, counts, n);
    k_scatter<<<nb, 256, 0, stream>>>(cid, cursor, counts, bucket, n);

    k_transpose2<<<C_NUM * 128 + C_NUM * 64, 256, 0, stream>>>(W1, Wt1, W2, Wt2);

    if (big) {
        k_convertlin<<<(n * D_IN / 8 + 255) / 256, 256, 0, stream>>>(x, xbl);
        k_gemm1b5<<<rowTiles64 * 4, 512, 0, stream>>>(xbl, Wt1, b1, bucket, counts, h1);
    } else {
        k_gemm1w<<<rowTiles64 * 4, 512, 0, stream>>>(x, Wt1, b1, bucket, counts, h1);
    }
    k_gemm2w<<<rowTiles64 * 4, 512, 0, stream>>>(h1, Wt2, b2, bucket, counts, pooled);

    k_tA<<<8, 256, 0, stream>>>(pooled, counts, Wfc, bfc, hfc);
    k_tB<<<4, 256, 0, stream>>>(hfc, Wa, ba, Wb, bb, Wc, scores);
    k_tCDE<<<16, 256, 0, stream>>>(scores, bc, hfc, Wrho, hr_raw, done,
                                   brho, Wcls, bcls, out);
}

// Round 14
// 125.805 us; speedup vs baseline: 1.0740x; 1.0740x over previous
//
#include <hip/hip_runtime.h>
#include <hip/hip_bf16.h>
#include <math.h>

// MIL_Cluster_FC round 14: R12 config + k_zero replaces hipMemsetAsync.
//  - rocprof showed fillBufferAligned(21.25KB) = 46us (!) in R7/R13 traces --
//    that's OUR header memset. Single-variable test: replace with a 1-block
//    zero kernel (~2us). Everything else = R12 (best fp32-direct config,
//    126us; gemm1w 76us invariant across occupancy experiments).

#define C_NUM 10
#define D_IN 1024
#define D_H 512
#define D_ATT 256
#define N_CLS 4
#define BM 128      // bucket region alignment
#define BMG 64      // gemm row tile
#define BN 128
#define BKS 64
#define ZERO_WORDS (16 + 16 + 16 + 16 + 256 + 5120)

typedef __attribute__((ext_vector_type(8))) short short8v;
typedef __attribute__((ext_vector_type(4))) short short4v;
typedef __attribute__((ext_vector_type(4))) float f32x4;

__device__ __forceinline__ short f2bf(float f) {
    __hip_bfloat16 h = __float2bfloat16(f);
    return *reinterpret_cast<short*>(&h);
}

__device__ __forceinline__ void gload_lds16(const void* g, void* l) {
    __builtin_amdgcn_global_load_lds((const __attribute__((address_space(1))) unsigned int*)g,
                                     (__attribute__((address_space(3))) unsigned int*)l,
                                     16, 0, 0);
}

// bijective XCD-chunked swizzle (m204)
__device__ __forceinline__ int xcd_swizzle(int orig, int nwg) {
    int q = nwg >> 3, r = nwg & 7;
    int xcd = orig & 7, base = orig >> 3;
    return (xcd < r ? xcd * (q + 1) : r * (q + 1) + (xcd - r) * q) + base;
}

// zero the 21KB workspace header (replaces 46us fillBufferAligned)
__global__ __launch_bounds__(1024) void k_zero(float* w) {
    for (int i = threadIdx.x; i < ZERO_WORDS; i += 1024) w[i] = 0.f;
}

// LDS-aggregated histogram
__global__ __launch_bounds__(256) void k_hist(const int* __restrict__ cid, int* counts, int n) {
    __shared__ int lc[C_NUM];
    int tid = threadIdx.x;
    if (tid < C_NUM) lc[tid] = 0;
    __syncthreads();
    int i = blockIdx.x * 256 + tid;
    if (i < n) atomicAdd(&lc[cid[i]], 1);
    __syncthreads();
    if (tid < C_NUM && lc[tid] > 0) atomicAdd(&counts[tid], lc[tid]);
}

// LDS-aggregated scatter + local prefix offsets + pad fill (block 0)
__global__ __launch_bounds__(256) void k_scatter(const int* __restrict__ cid, int* cursor,
                                                 const int* __restrict__ counts,
                                                 int* bucket, int n) {
    __shared__ int lc[C_NUM];
    __shared__ int basev[C_NUM];
    __shared__ int loff[C_NUM + 1];
    int tid = threadIdx.x;
    if (tid < C_NUM) lc[tid] = 0;
    if (tid == 0) {
        int off = 0;
        for (int c2 = 0; c2 < C_NUM; ++c2) {
            loff[c2] = off;
            off += ((counts[c2] + BM - 1) / BM) * BM;
        }
        loff[C_NUM] = off;
    }
    __syncthreads();
    int i = blockIdx.x * 256 + tid;
    int c = 0, lpos = 0;
    bool valid = (i < n);
    if (valid) { c = cid[i]; lpos = atomicAdd(&lc[c], 1); }
    __syncthreads();
    if (tid < C_NUM) basev[tid] = (lc[tid] > 0) ? atomicAdd(&cursor[tid], lc[tid]) : 0;
    __syncthreads();
    if (valid) bucket[loff[c] + basev[c] + lpos] = i;
    if (blockIdx.x == 0) {
        for (int c2 = 0; c2 < C_NUM; ++c2)
            for (int p = loff[c2] + counts[c2] + tid; p < loff[c2 + 1]; p += 256)
                bucket[p] = -1;
    }
}

// merged W1+W2 transpose: [C][K][N] fp32 -> [C][N][K] bf16
__global__ __launch_bounds__(256) void k_transpose2(
    const float* __restrict__ W1, short* __restrict__ Wt1,
    const float* __restrict__ W2, short* __restrict__ Wt2)
{
    __shared__ float t[64][65];
    int bid = blockIdx.x;
    const float* src; short* dst; int K, N, k0, n0;
    if (bid < C_NUM * 128) {
        int cc = bid >> 7, r = bid & 127;
        k0 = (r & 15) * 64; n0 = (r >> 4) * 64;
        src = W1 + (size_t)cc * D_IN * D_H; dst = Wt1 + (size_t)cc * D_H * D_IN;
        K = D_IN; N = D_H;
    } else {
        int idx = bid - C_NUM * 128;
        int cc = idx >> 6, r = idx & 63;
        k0 = (r & 7) * 64; n0 = (r >> 3) * 64;
        src = W2 + (size_t)cc * D_H * D_H; dst = Wt2 + (size_t)cc * D_H * D_H;
        K = D_H; N = D_H;
    }
    int tid = threadIdx.x;
    int tk = tid >> 4, tn4 = (tid & 15) * 4;
#pragma unroll
    for (int it = 0; it < 4; ++it) {
        int k = tk + it * 16;
        f32x4 v = *(const f32x4*)&src[(size_t)(k0 + k) * N + n0 + tn4];
        t[k][tn4 + 0] = v[0]; t[k][tn4 + 1] = v[1];
        t[k][tn4 + 2] = v[2]; t[k][tn4 + 3] = v[3];
    }
    __syncthreads();
    int wn = tid >> 2, kq = (tid & 3) * 16;
#pragma unroll
    for (int q = 0; q < 4; ++q) {
        int k = kq + q * 4;
        short4v o;
#pragma unroll
        for (int e = 0; e < 4; ++e) o[e] = f2bf(t[k + e][wn]);
        *(short4v*)&dst[(size_t)(n0 + wn) * K + k0 + k] = o;
    }
}

// gemm1: 512 threads, 8 waves (2x4), 64x128 tile, fp32-direct A (R12-proven).
// h1 = relu(x[bucket] @ W1t^T + b1)
__global__ __launch_bounds__(512) void k_gemm1w(
    const float* __restrict__ x, const short* __restrict__ Wt, const float* __restrict__ b1,
    const int* __restrict__ bucket, const int* __restrict__ counts, short* __restrict__ h1)
{
    __shared__ float Asf[BMG * BKS];   // 16 KB fp32
    __shared__ short Bs[BN * BKS];     // 16 KB bf16
    __shared__ int ridx[BMG];
    __shared__ int saoff[C_NUM + 1];

    int tid = threadIdx.x;
    int wg = xcd_swizzle(blockIdx.x, gridDim.x);
    int rowStart = (wg >> 2) * BMG;
    int colStart = (wg & 3) * BN;

    if (tid == 0) {
        int off = 0;
        for (int c2 = 0; c2 < C_NUM; ++c2) {
            saoff[c2] = off;
            off += ((counts[c2] + BM - 1) / BM) * BM;
        }
        saoff[C_NUM] = off;
    }
    if (tid < BMG) ridx[tid] = bucket[rowStart + tid];
    __syncthreads();
    if (rowStart >= saoff[C_NUM]) return;
    int c = 0;
    while (c < C_NUM - 1 && rowStart >= saoff[c + 1]) ++c;

    int lane = tid & 63;
    int wid = tid >> 6;          // 0..7
    int wm = wid >> 2;           // 0..1
    int wn = wid & 3;            // 0..3

    const float* aq[2];
#pragma unroll
    for (int q = 0; q < 2; ++q) {
        int row = q * 32 + wid * 4 + (lane >> 4);
        int rr = ridx[row];
        int srcslot = (lane & 15) ^ (row & 15);
        aq[q] = x + (size_t)(rr < 0 ? 0 : rr) * D_IN + srcslot * 4;
    }
    int l8 = lane >> 3;
    int sslot = (lane & 7) ^ l8;
    const short* bq[2];
#pragma unroll
    for (int q = 0; q < 2; ++q) {
        int rowb = q * 64 + wid * 8 + l8;
        bq[q] = Wt + ((size_t)c * D_H + colStart + rowb) * D_IN + sslot * 8;
    }

    f32x4 acc[2][2];
#pragma unroll
    for (int i = 0; i < 2; ++i)
#pragma unroll
        for (int j = 0; j < 2; ++j)
            acc[i][j] = f32x4{0.f, 0.f, 0.f, 0.f};

    for (int k0 = 0; k0 < D_IN; k0 += BKS) {
        gload_lds16(bq[0] + k0, &Bs[(wid * 8) * BKS]);
        gload_lds16(bq[1] + k0, &Bs[(64 + wid * 8) * BKS]);
        gload_lds16(aq[0] + k0, &Asf[(wid * 4) * BKS]);
        gload_lds16(aq[1] + k0, &Asf[(32 + wid * 4) * BKS]);
        __syncthreads();
#pragma unroll
        for (int kk = 0; kk < 2; ++kk) {
            short8v af[2], bfr[2];
#pragma unroll
            for (int i = 0; i < 2; ++i) {
                int row = wm * 32 + i * 16 + (lane & 15);
                int s8 = kk * 4 + (lane >> 4);
                int p0 = (2 * s8) ^ (row & 15);
                int p1 = (2 * s8 + 1) ^ (row & 15);
                f32x4 lo = *(const f32x4*)&Asf[row * BKS + p0 * 4];
                f32x4 hi = *(const f32x4*)&Asf[row * BKS + p1 * 4];
                short8v v;
#pragma unroll
                for (int e = 0; e < 4; ++e) { v[e] = f2bf(lo[e]); v[4 + e] = f2bf(hi[e]); }
                af[i] = v;
            }
#pragma unroll
            for (int j = 0; j < 2; ++j) {
                int nn = wn * 32 + j * 16 + (lane & 15);
                int slot = (kk * 4 + (lane >> 4)) ^ (nn & 7);
                bfr[j] = *(const short8v*)&Bs[nn * BKS + slot * 8];
            }
#pragma unroll
            for (int i = 0; i < 2; ++i)
#pragma unroll
                for (int j = 0; j < 2; ++j)
                    acc[i][j] = __builtin_amdgcn_mfma_f32_16x16x32_bf16(af[i], bfr[j], acc[i][j], 0, 0, 0);
        }
        __syncthreads();
    }

    const float* bias = b1 + c * D_H;
    float bj[2];
#pragma unroll
    for (int j = 0; j < 2; ++j) bj[j] = bias[colStart + wn * 32 + j * 16 + (lane & 15)];
#pragma unroll
    for (int i = 0; i < 2; ++i) {
#pragma unroll
        for (int r = 0; r < 4; ++r) {
            int rowl = wm * 32 + i * 16 + (lane >> 4) * 4 + r;
            bool valid = (ridx[rowl] >= 0);
            size_t gro = (size_t)(rowStart + rowl) * D_H + colStart + wn * 32 + (lane & 15);
#pragma unroll
            for (int j = 0; j < 2; ++j) {
                float v = valid ? fmaxf(acc[i][j][r] + bj[j], 0.f) : 0.f;
                h1[gro + j * 16] = f2bf(v);
            }
        }
    }
}

// gemm2: 512 threads, 8 waves, 64x128 tile (R12-proven)
__global__ __launch_bounds__(512) void k_gemm2w(
    const short* __restrict__ h1, const short* __restrict__ Wt, const float* __restrict__ b2,
    const int* __restrict__ bucket, const int* __restrict__ counts, float* __restrict__ pooled)
{
    __shared__ short As[BMG * BKS];
    __shared__ short Bs[BN * BKS];
    __shared__ int ridx[BMG];
    __shared__ int saoff[C_NUM + 1];

    int tid = threadIdx.x;
    int wg = xcd_swizzle(blockIdx.x, gridDim.x);
    int rowStart = (wg >> 2) * BMG;
    int colStart = (wg & 3) * BN;

    if (tid == 0) {
        int off = 0;
        for (int c2 = 0; c2 < C_NUM; ++c2) {
            saoff[c2] = off;
            off += ((counts[c2] + BM - 1) / BM) * BM;
        }
        saoff[C_NUM] = off;
    }
    if (tid < BMG) ridx[tid] = bucket[rowStart + tid];
    __syncthreads();
    if (rowStart >= saoff[C_NUM]) return;
    int c = 0;
    while (c < C_NUM - 1 && rowStart >= saoff[c + 1]) ++c;

    int lane = tid & 63;
    int wid = tid >> 6;
    int wm = wid >> 2, wn = wid & 3;

    int l8 = lane >> 3;
    int sslot = (lane & 7) ^ l8;
    const short* abase = h1 + (size_t)(rowStart + wid * 8 + l8) * D_H + sslot * 8;
    const short* bq[2];
#pragma unroll
    for (int q = 0; q < 2; ++q) {
        int rowb = q * 64 + wid * 8 + l8;
        bq[q] = Wt + ((size_t)c * D_H + colStart + rowb) * D_H + sslot * 8;
    }

    f32x4 acc[2][2];
#pragma unroll
    for (int i = 0; i < 2; ++i)
#pragma unroll
        for (int j = 0; j < 2; ++j)
            acc[i][j] = f32x4{0.f, 0.f, 0.f, 0.f};

    for (int k0 = 0; k0 < D_H; k0 += BKS) {
        gload_lds16(abase + k0, &As[(wid * 8) * BKS]);
        gload_lds16(bq[0] + k0, &Bs[(wid * 8) * BKS]);
        gload_lds16(bq[1] + k0, &Bs[(64 + wid * 8) * BKS]);
        __syncthreads();
#pragma unroll
        for (int kk = 0; kk < 2; ++kk) {
            short8v af[2], bfr[2];
#pragma unroll
            for (int i = 0; i < 2; ++i) {
                int row = wm * 32 + i * 16 + (lane & 15);
                int slot = (kk * 4 + (lane >> 4)) ^ (row & 7);
                af[i] = *(const short8v*)&As[row * BKS + slot * 8];
            }
#pragma unroll
            for (int j = 0; j < 2; ++j) {
                int nn = wn * 32 + j * 16 + (lane & 15);
                int slot = (kk * 4 + (lane >> 4)) ^ (nn & 7);
                bfr[j] = *(const short8v*)&Bs[nn * BKS + slot * 8];
            }
#pragma unroll
            for (int i = 0; i < 2; ++i)
#pragma unroll
                for (int j = 0; j < 2; ++j)
                    acc[i][j] = __builtin_amdgcn_mfma_f32_16x16x32_bf16(af[i], bfr[j], acc[i][j], 0, 0, 0);
        }
        __syncthreads();
    }

    const float* bias = b2 + c * D_H;
    float bj[2];
#pragma unroll
    for (int j = 0; j < 2; ++j) bj[j] = bias[colStart + wn * 32 + j * 16 + (lane & 15)];
    float csum[2] = {0.f, 0.f};
#pragma unroll
    for (int i = 0; i < 2; ++i) {
#pragma unroll
        for (int r = 0; r < 4; ++r) {
            int rowl = wm * 32 + i * 16 + (lane >> 4) * 4 + r;
            float m = (ridx[rowl] >= 0) ? 1.f : 0.f;
#pragma unroll
            for (int j = 0; j < 2; ++j)
                csum[j] += m * fmaxf(acc[i][j][r] + bj[j], 0.f);
        }
    }
#pragma unroll
    for (int j = 0; j < 2; ++j) {
        float s = csum[j];
        s += __shfl_xor(s, 16, 64);
        s += __shfl_xor(s, 32, 64);
        if ((lane >> 4) == 0)
            atomicAdd(&pooled[c * D_H + colStart + wn * 32 + j * 16 + lane], s);
    }
}

// ---- tail stage A ----
__global__ __launch_bounds__(256) void k_tA(
    const float* __restrict__ pooled, const int* __restrict__ counts,
    const float* __restrict__ Wfc, const float* __restrict__ bfc,
    float* __restrict__ hfc)
{
    __shared__ float hcs[C_NUM][D_H];
    __shared__ float red[4][64][C_NUM];
    int tid = threadIdx.x;
    for (int idx = tid; idx < C_NUM * D_H; idx += 256) {
        int cc = idx >> 9;
        hcs[cc][idx & (D_H - 1)] = pooled[idx] / fmaxf((float)counts[cc], 1.f);
    }
    __syncthreads();
    int col = blockIdx.x * 64 + (tid & 63);
    int kq = tid >> 6, k0 = kq * 128;
    float acc[C_NUM] = {};
    for (int k = 0; k < 128; ++k) {
        float wv = Wfc[(size_t)(k0 + k) * D_H + col];
#pragma unroll
        for (int cc = 0; cc < C_NUM; ++cc) acc[cc] += hcs[cc][k0 + k] * wv;
    }
#pragma unroll
    for (int cc = 0; cc < C_NUM; ++cc) red[kq][tid & 63][cc] = acc[cc];
    __syncthreads();
    if (kq == 0) {
        float bv = bfc[col];
#pragma unroll
        for (int cc = 0; cc < C_NUM; ++cc) {
            float s = red[0][tid][cc] + red[1][tid][cc] + red[2][tid][cc] + red[3][tid][cc];
            hfc[cc * D_H + col] = fmaxf(s + bv, 0.f);
        }
    }
}

// ---- tail stage B ----
__global__ __launch_bounds__(256) void k_tB(
    const float* __restrict__ hfc,
    const float* __restrict__ Wa, const float* __restrict__ ba,
    const float* __restrict__ Wb, const float* __restrict__ bb,
    const float* __restrict__ Wc,
    float* __restrict__ scores)
{
    __shared__ float hfs[C_NUM][D_H];
    __shared__ float red[4][64][C_NUM][2];
    int tid = threadIdx.x;
    for (int idx = tid; idx < C_NUM * D_H; idx += 256) {
        hfs[idx >> 9][idx & (D_H - 1)] = hfc[idx];
    }
    __syncthreads();
    int ad = blockIdx.x * 64 + (tid & 63);
    int kq = tid >> 6, k0 = kq * 128;
    float sa[C_NUM] = {}, sb[C_NUM] = {};
    for (int k = 0; k < 128; ++k) {
        float wav = Wa[(size_t)(k0 + k) * D_ATT + ad];
        float wbv = Wb[(size_t)(k0 + k) * D_ATT + ad];
#pragma unroll
        for (int cc = 0; cc < C_NUM; ++cc) {
            float h = hfs[cc][k0 + k];
            sa[cc] += h * wav;
            sb[cc] += h * wbv;
        }
    }
#pragma unroll
    for (int cc = 0; cc < C_NUM; ++cc) {
        red[kq][tid & 63][cc][0] = sa[cc];
        red[kq][tid & 63][cc][1] = sb[cc];
    }
    __syncthreads();
    if (kq == 0) {
        float bav = ba[ad], bbv = bb[ad], wcv = Wc[ad];
#pragma unroll
        for (int cc = 0; cc < C_NUM; ++cc) {
            float sat = red[0][tid][cc][0] + red[1][tid][cc][0] + red[2][tid][cc][0] + red[3][tid][cc][0];
            float sbt = red[0][tid][cc][1] + red[1][tid][cc][1] + red[2][tid][cc][1] + red[3][tid][cc][1];
            float v = tanhf(sat + bav) * (1.f / (1.f + expf(-(sbt + bbv)))) * wcv;
            v += __shfl_xor(v, 1, 64); v += __shfl_xor(v, 2, 64); v += __shfl_xor(v, 4, 64);
            v += __shfl_xor(v, 8, 64); v += __shfl_xor(v, 16, 64); v += __shfl_xor(v, 32, 64);
            if (tid == 0) atomicAdd(&scores[cc], v);
        }
    }
}

// ---- tail C+D+E fused (last-block-done) ----
__global__ __launch_bounds__(256) void k_tCDE(
    const float* __restrict__ scores, const float* __restrict__ bc,
    const float* __restrict__ hfc, const float* __restrict__ Wrho,
    float* __restrict__ hr_raw, int* __restrict__ done,
    const float* __restrict__ brho,
    const float* __restrict__ Wcls, const float* __restrict__ bcls,
    float* __restrict__ out)
{
    __shared__ float hps[32];
    __shared__ int amLast;
    int tid = threadIdx.x;
    int k0 = blockIdx.x * 32;
    if (tid < 32) {
        float sc2[C_NUM];
        float mx = -1e30f;
#pragma unroll
        for (int cc = 0; cc < C_NUM; ++cc) { sc2[cc] = scores[cc] + bc[0]; mx = fmaxf(mx, sc2[cc]); }
        float sum = 0.f;
#pragma unroll
        for (int cc = 0; cc < C_NUM; ++cc) { sc2[cc] = expf(sc2[cc] - mx); sum += sc2[cc]; }
        float s = 0.f;
#pragma unroll
        for (int cc = 0; cc < C_NUM; ++cc) s += (sc2[cc] / sum) * hfc[cc * D_H + k0 + tid];
        hps[tid] = s;
    }
    __syncthreads();
    float acc = 0.f;
#pragma unroll 8
    for (int k = 0; k < 32; ++k)
        acc += hps[k] * Wrho[(size_t)(k0 + k) * D_ATT + tid];
    atomicAdd(&hr_raw[tid], acc);

    __threadfence();
    if (tid == 0) amLast = (atomicAdd(done, 1) == (int)gridDim.x - 1);
    __syncthreads();
    if (!amLast) return;

    __shared__ float cpart[4][N_CLS];
    int lane = tid & 63, w = tid >> 6;
    float hraw = atomicAdd(&hr_raw[tid], 0.f);
    float h = fmaxf(hraw + brho[tid], 0.f);
    f32x4 wv = *(const f32x4*)&Wcls[tid * N_CLS];
    float v[N_CLS];
#pragma unroll
    for (int l = 0; l < N_CLS; ++l) {
        v[l] = h * wv[l];
        v[l] += __shfl_xor(v[l], 1, 64); v[l] += __shfl_xor(v[l], 2, 64);
        v[l] += __shfl_xor(v[l], 4, 64); v[l] += __shfl_xor(v[l], 8, 64);
        v[l] += __shfl_xor(v[l], 16, 64); v[l] += __shfl_xor(v[l], 32, 64);
    }
    if (lane == 0) {
#pragma unroll
        for (int l = 0; l < N_CLS; ++l) cpart[w][l] = v[l];
    }
    __syncthreads();
    if (tid == 0) {
        float lg[N_CLS];
#pragma unroll
        for (int l = 0; l < N_CLS; ++l)
            lg[l] = cpart[0][l] + cpart[1][l] + cpart[2][l] + cpart[3][l] + bcls[l];
        int best = 0;
#pragma unroll
        for (int l = 1; l < N_CLS; ++l) if (lg[l] > lg[best]) best = l;
        float Sv = 1.f;
#pragma unroll
        for (int l = 0; l < N_CLS; ++l) {
            float hz = 1.f / (1.f + expf(-lg[l]));
            out[l] = hz;
            Sv *= (1.f - hz);
            out[4 + l] = Sv;
        }
        out[8] = (float)best;
    }
}

extern "C" void kernel_launch(void* const* d_in, const int* in_sizes, int n_in,
                              void* d_out, int out_size, void* d_ws, size_t ws_size,
                              hipStream_t stream)
{
    const float* x    = (const float*)d_in[0];
    const int*   cid  = (const int*)d_in[1];
    const float* W1   = (const float*)d_in[2];
    const float* b1   = (const float*)d_in[3];
    const float* W2   = (const float*)d_in[4];
    const float* b2   = (const float*)d_in[5];
    const float* Wfc  = (const float*)d_in[6];
    const float* bfc  = (const float*)d_in[7];
    const float* Wa   = (const float*)d_in[8];
    const float* ba   = (const float*)d_in[9];
    const float* Wb   = (const float*)d_in[10];
    const float* bb   = (const float*)d_in[11];
    const float* Wc   = (const float*)d_in[12];
    const float* bc   = (const float*)d_in[13];
    const float* Wrho = (const float*)d_in[14];
    const float* brho = (const float*)d_in[15];
    const float* Wcls = (const float*)d_in[16];
    const float* bcls = (const float*)d_in[17];
    float* out = (float*)d_out;

    int n = in_sizes[0] / D_IN;                       // 20000
    int rowTiles = (n + BM - 1) / BM + C_NUM;         // 128-aligned worst case
    int npadMax = rowTiles * BM;
    int rowTiles64 = rowTiles * 2;

    // workspace layout; header zeroed by k_zero (NOT hipMemsetAsync)
    char* w = (char*)d_ws;
    int* counts   = (int*)w;                          // [16]
    int* cursor   = counts + 16;                      // [16]
    float* scores = (float*)(counts + 32);            // [16]
    int* done     = (int*)(scores + 16);              // [16]
    float* hr_raw = (float*)(done + 16);              // [256]
    float* pooled = hr_raw + 256;                     // [5120]
    float* hfc  = pooled + 5120;                      // [5120]
    int* bucket = (int*)(hfc + 5120);                 // [npadMax]
    short* Wt1 = (short*)(bucket + npadMax);          // C*512*1024
    short* Wt2 = Wt1 + (size_t)C_NUM * D_H * D_IN;    // C*512*512
    short* h1  = Wt2 + (size_t)C_NUM * D_H * D_H;     // npadMax*512

    k_zero<<<1, 1024, 0, stream>>>((float*)w);

    int nb = (n + 255) / 256;
    k_hist<<<nb, 256, 0, stream>>>(cid, counts, n);
    k_scatter<<<nb, 256, 0, stream>>>(cid, cursor, counts, bucket, n);

    k_transpose2<<<C_NUM * 128 + C_NUM * 64, 256, 0, stream>>>(W1, Wt1, W2, Wt2);

    k_gemm1w<<<rowTiles64 * 4, 512, 0, stream>>>(x, Wt1, b1, bucket, counts, h1);
    k_gemm2w<<<rowTiles64 * 4, 512, 0, stream>>>(h1, Wt2, b2, bucket, counts, pooled);

    k_tA<<<8, 256, 0, stream>>>(pooled, counts, Wfc, bfc, hfc);
    k_tB<<<4, 256, 0, stream>>>(hfc, Wa, ba, Wb, bb, Wc, scores);
    k_tCDE<<<16, 256, 0, stream>>>(scores, bc, hfc, Wrho, hr_raw, done,
                                   brho, Wcls, bcls, out);
}